// Round 5
// baseline (2461.090 us; speedup 1.0000x reference)
//
#include <hip/hip_runtime.h>
#include <hip/hip_bf16.h>
#include <math.h>

#define N_NODES 100000
#define N_EDGES 1600000
#define F0 32
#define F1 16
#define F2 8
#define NCLS 6
#define NGRAPH 64
#define NT 256
#define NB 768                 // 3 blocks/CU needed; __launch_bounds__(256,4) gives 4/CU capacity -> co-residency guaranteed
#define GT (NB * NT)

// ---- device-scope grid barrier: monotonic counter, no reset needed ----
// __threadfence() (agent seq fence) = release (wbl2: flush this XCD's dirty
// L2) before arrival, acquire (inv: invalidate stale L1/L2) after the spin.
// f32 atomicAdd / __hip_atomic ops are device-scope -> coherent across XCDs.
__device__ inline void gbar(int* bar, int target) {
    __syncthreads();
    if (threadIdx.x == 0) {
        __threadfence();
        __hip_atomic_fetch_add(bar, 1, __ATOMIC_RELAXED, __HIP_MEMORY_SCOPE_AGENT);
        while (__hip_atomic_load(bar, __ATOMIC_RELAXED, __HIP_MEMORY_SCOPE_AGENT) < target)
            __builtin_amdgcn_s_sleep(8);
        __threadfence();
    }
    __syncthreads();
}

__global__ __launch_bounds__(NT, 4) void fused_k(
    const float* __restrict__ x, const int* __restrict__ ei, const int* __restrict__ batch,
    const float* __restrict__ W1a, const float* __restrict__ b1a,
    const float* __restrict__ W1b, const float* __restrict__ b1b,
    const float* __restrict__ W2a, const float* __restrict__ b2a,
    const float* __restrict__ W2b, const float* __restrict__ b2b,
    const float* __restrict__ Wfc, const float* __restrict__ bfc,
    float* __restrict__ xw1, float* __restrict__ agg1,
    float* __restrict__ h1w, float* __restrict__ agg2,
    float* __restrict__ gsum, float* __restrict__ gcnt,
    int* __restrict__ bar, float* __restrict__ out)
{
    __shared__ float sW1a[F0 * F1], sW1b[F1 * F1], sW2a[F1 * F2], sW2b[F2 * F2];
    __shared__ float sb1a[F1], sb1b[F1], sb2a[F2], sb2b[F2];
    __shared__ float ls[NGRAPH * F2];
    __shared__ float lc[NGRAPH];

    const int t = threadIdx.x;
    const int gid = blockIdx.x * NT + t;

    // stage all weights once
    for (int i = t; i < F0 * F1; i += NT) sW1a[i] = W1a[i];
    for (int i = t; i < F1 * F1; i += NT) sW1b[i] = W1b[i];
    for (int i = t; i < F1 * F2; i += NT) sW2a[i] = W2a[i];
    for (int i = t; i < F2 * F2; i += NT) sW2b[i] = W2b[i];
    if (t < F1) { sb1a[t] = b1a[t]; sb1b[t] = b1b[t]; }
    if (t < F2) { sb2a[t] = b2a[t]; sb2b[t] = b2b[t]; }
    for (int i = t; i < NGRAPH * F2; i += NT) ls[i] = 0.0f;
    if (t < NGRAPH) lc[t] = 0.0f;
    __syncthreads();

    // ---- P0: xw1 = x @ W1a (project 32->16 BEFORE scatter) ----
    for (int n = gid; n < N_NODES; n += GT) {
        float xi[F0];
        const float4* xp = (const float4*)(x + (size_t)n * F0);
#pragma unroll
        for (int q = 0; q < 8; q++) {
            float4 v = xp[q];
            xi[4 * q] = v.x; xi[4 * q + 1] = v.y; xi[4 * q + 2] = v.z; xi[4 * q + 3] = v.w;
        }
#pragma unroll
        for (int j = 0; j < F1; j++) {
            float s = 0.0f;
#pragma unroll
            for (int k = 0; k < F0; k++) s += xi[k] * sW1a[k * F1 + j];
            xw1[(size_t)n * F1 + j] = s;
        }
    }
    gbar(bar, NB * 1);

    // ---- P1: agg1[dst] += xw1[src] (16 f32 atomics per edge) ----
    for (int e = gid; e < N_EDGES; e += GT) {
        int src = ei[e];
        int dst = ei[N_EDGES + e];
        const float4* vs = (const float4*)(xw1 + (size_t)src * F1);
        float4 a = vs[0], b = vs[1], c = vs[2], d = vs[3];
        float* ag = agg1 + (size_t)dst * F1;
        atomicAdd(ag + 0, a.x);  atomicAdd(ag + 1, a.y);
        atomicAdd(ag + 2, a.z);  atomicAdd(ag + 3, a.w);
        atomicAdd(ag + 4, b.x);  atomicAdd(ag + 5, b.y);
        atomicAdd(ag + 6, b.z);  atomicAdd(ag + 7, b.w);
        atomicAdd(ag + 8, c.x);  atomicAdd(ag + 9, c.y);
        atomicAdd(ag + 10, c.z); atomicAdd(ag + 11, c.w);
        atomicAdd(ag + 12, d.x); atomicAdd(ag + 13, d.y);
        atomicAdd(ag + 14, d.z); atomicAdd(ag + 15, d.w);
    }
    gbar(bar, NB * 2);

    // ---- P2: u=relu(xw1+agg1+b1a); h=relu(u@W1b+b1b); h1w = h@W2a ----
    for (int n = gid; n < N_NODES; n += GT) {
        float u[F1];
#pragma unroll
        for (int k = 0; k < F1; k++)
            u[k] = fmaxf(xw1[(size_t)n * F1 + k] + agg1[(size_t)n * F1 + k] + sb1a[k], 0.0f);
        float h[F1];
#pragma unroll
        for (int j = 0; j < F1; j++) {
            float s = sb1b[j];
#pragma unroll
            for (int k = 0; k < F1; k++) s += u[k] * sW1b[k * F1 + j];
            h[j] = fmaxf(s, 0.0f);
        }
#pragma unroll
        for (int j = 0; j < F2; j++) {
            float s = 0.0f;
#pragma unroll
            for (int k = 0; k < F1; k++) s += h[k] * sW2a[k * F2 + j];
            h1w[(size_t)n * F2 + j] = s;
        }
    }
    gbar(bar, NB * 3);

    // ---- P3: agg2[dst] += h1w[src] (8 f32 atomics per edge) ----
    for (int e = gid; e < N_EDGES; e += GT) {
        int src = ei[e];
        int dst = ei[N_EDGES + e];
        const float4* vs = (const float4*)(h1w + (size_t)src * F2);
        float4 a = vs[0], b = vs[1];
        float* ag = agg2 + (size_t)dst * F2;
        atomicAdd(ag + 0, a.x); atomicAdd(ag + 1, a.y);
        atomicAdd(ag + 2, a.z); atomicAdd(ag + 3, a.w);
        atomicAdd(ag + 4, b.x); atomicAdd(ag + 5, b.y);
        atomicAdd(ag + 6, b.z); atomicAdd(ag + 7, b.w);
    }
    gbar(bar, NB * 4);

    // ---- P4: layer-2 tail + mean-pool partials (LDS) + flush ----
    for (int n = gid; n < N_NODES; n += GT) {
        float u[F2];
#pragma unroll
        for (int k = 0; k < F2; k++)
            u[k] = fmaxf(h1w[(size_t)n * F2 + k] + agg2[(size_t)n * F2 + k] + sb2a[k], 0.0f);
        float v[F2];
#pragma unroll
        for (int j = 0; j < F2; j++) {
            float s = sb2b[j];
#pragma unroll
            for (int k = 0; k < F2; k++) s += u[k] * sW2b[k * F2 + j];
            v[j] = fmaxf(s, 0.0f);
        }
        int g = batch[n];
#pragma unroll
        for (int j = 0; j < F2; j++) atomicAdd(&ls[g * F2 + j], v[j]);
        atomicAdd(&lc[g], 1.0f);
    }
    __syncthreads();
    for (int i = t; i < NGRAPH * F2; i += NT)
        if (ls[i] != 0.0f) atomicAdd(&gsum[i], ls[i]);
    if (t < NGRAPH && lc[t] != 0.0f) atomicAdd(&gcnt[t], lc[t]);
    gbar(bar, NB * 5);

    // ---- P5: FC + log_softmax (block 0 only) ----
    if (blockIdx.x == 0 && t < NGRAPH) {
        int g = t;
        float cnt = fmaxf(gcnt[g], 1.0f);
        float p[F2];
#pragma unroll
        for (int f = 0; f < F2; f++) p[f] = gsum[g * F2 + f] / cnt;
        float l[NCLS];
#pragma unroll
        for (int c = 0; c < NCLS; c++) {
            float s = bfc[c];
#pragma unroll
            for (int f = 0; f < F2; f++) s += p[f] * Wfc[f * NCLS + c];
            l[c] = s;
        }
        float m = -INFINITY;
#pragma unroll
        for (int c = 0; c < NCLS; c++) m = fmaxf(m, l[c]);
        float s = 0.0f;
#pragma unroll
        for (int c = 0; c < NCLS; c++) s += expf(l[c] - m);
        float lse = m + logf(s);
#pragma unroll
        for (int c = 0; c < NCLS; c++) out[g * NCLS + c] = l[c] - lse;
    }
}

extern "C" void kernel_launch(void* const* d_in, const int* in_sizes, int n_in,
                              void* d_out, int out_size, void* d_ws, size_t ws_size,
                              hipStream_t stream) {
    const float* x    = (const float*)d_in[0];
    const int*   ei   = (const int*)d_in[1];
    const int*   batch= (const int*)d_in[2];
    const float* W1a  = (const float*)d_in[3];
    const float* b1a  = (const float*)d_in[4];
    const float* W1b  = (const float*)d_in[5];
    const float* b1b  = (const float*)d_in[6];
    const float* W2a  = (const float*)d_in[7];
    const float* b2a  = (const float*)d_in[8];
    const float* W2b  = (const float*)d_in[9];
    const float* b2b  = (const float*)d_in[10];
    const float* Wfc  = (const float*)d_in[11];
    const float* bfc  = (const float*)d_in[12];
    float* out = (float*)d_out;

    // workspace layout (zeroed region first: agg1|agg2|gsum|gcnt|bar)
    float* ws   = (float*)d_ws;
    float* agg1 = ws;                                   // 100000*16
    float* agg2 = agg1 + (size_t)N_NODES * F1;          // 100000*8
    float* gsum = agg2 + (size_t)N_NODES * F2;          // 64*8
    float* gcnt = gsum + NGRAPH * F2;                   // 64
    int*   bar  = (int*)(gcnt + NGRAPH);                // 16 ints
    float* xw1  = (float*)(bar + 16);                   // 100000*16
    float* h1w  = xw1 + (size_t)N_NODES * F1;           // 100000*8

    size_t zero_bytes = ((size_t)N_NODES * (F1 + F2) + NGRAPH * F2 + NGRAPH) * sizeof(float)
                        + 16 * sizeof(int);
    hipMemsetAsync(agg1, 0, zero_bytes, stream);

    fused_k<<<NB, NT, 0, stream>>>(x, ei, batch,
                                   W1a, b1a, W1b, b1b, W2a, b2a, W2b, b2b, Wfc, bfc,
                                   xw1, agg1, h1w, agg2, gsum, gcnt, bar, out);
}

// Round 6
// 994.778 us; speedup vs baseline: 2.4740x; 2.4740x over previous
//
#include <hip/hip_runtime.h>
#include <hip/hip_bf16.h>
#include <math.h>

#define N_NODES 100000
#define N_EDGES 1600000
#define F0 32
#define F1 16
#define F2 8
#define NCLS 6
#define NGRAPH 64
#define NT 256
#define NB 1024                // 4 blocks/CU on 256 CUs; launch_bounds(256,4) guarantees capacity
#define GT (NB * NT)

// ---- device-scope grid barrier: monotonic counter, no reset needed ----
__device__ inline void gbar(int* bar, int target) {
    __syncthreads();
    if (threadIdx.x == 0) {
        __threadfence();   // release: flush dirty lines before arrival
        __hip_atomic_fetch_add(bar, 1, __ATOMIC_RELAXED, __HIP_MEMORY_SCOPE_AGENT);
        while (__hip_atomic_load(bar, __ATOMIC_RELAXED, __HIP_MEMORY_SCOPE_AGENT) < target)
            __builtin_amdgcn_s_sleep(8);
        __threadfence();   // acquire: invalidate stale caches after release
    }
    __syncthreads();
}

__global__ __launch_bounds__(NT, 4) void fused_k(
    const float* __restrict__ x, const int* __restrict__ ei, const int* __restrict__ batch,
    const float* __restrict__ W1a, const float* __restrict__ b1a,
    const float* __restrict__ W1b, const float* __restrict__ b1b,
    const float* __restrict__ W2a, const float* __restrict__ b2a,
    const float* __restrict__ W2b, const float* __restrict__ b2b,
    const float* __restrict__ Wfc, const float* __restrict__ bfc,
    float* __restrict__ xw1, float* __restrict__ agg1,
    float* __restrict__ h1w, float* __restrict__ agg2,
    float* __restrict__ gsum, float* __restrict__ gcnt,
    int* __restrict__ bar, float* __restrict__ out)
{
    __shared__ float sW1a[F0 * F1], sW1b[F1 * F1], sW2a[F1 * F2], sW2b[F2 * F2];
    __shared__ float sb1a[F1], sb1b[F1], sb2a[F2], sb2b[F2];
    __shared__ float ls[NGRAPH * F2];
    __shared__ float lc[NGRAPH];

    const int t = threadIdx.x;
    const int gid = blockIdx.x * NT + t;

    for (int i = t; i < F0 * F1; i += NT) sW1a[i] = W1a[i];
    for (int i = t; i < F1 * F1; i += NT) sW1b[i] = W1b[i];
    for (int i = t; i < F1 * F2; i += NT) sW2a[i] = W2a[i];
    for (int i = t; i < F2 * F2; i += NT) sW2b[i] = W2b[i];
    if (t < F1) { sb1a[t] = b1a[t]; sb1b[t] = b1b[t]; }
    if (t < F2) { sb2a[t] = b2a[t]; sb2b[t] = b2b[t]; }
    for (int i = t; i < NGRAPH * F2; i += NT) ls[i] = 0.0f;
    if (t < NGRAPH) lc[t] = 0.0f;
    __syncthreads();

    // ---- P0a: zero agg1|agg2 (adjacent in ws; 2.4M floats) ----
    {
        float4 z = make_float4(0.f, 0.f, 0.f, 0.f);
        float4* az = (float4*)agg1;   // covers agg1 then agg2
        const int nz = N_NODES * (F1 + F2) / 4;
        for (int i = gid; i < nz; i += GT) az[i] = z;
    }
    // ---- P0b: xw1 = x @ W1a (project 32->16 BEFORE scatter) ----
    for (int n = gid; n < N_NODES; n += GT) {
        float xi[F0];
        const float4* xp = (const float4*)(x + (size_t)n * F0);
#pragma unroll
        for (int q = 0; q < 8; q++) {
            float4 v = xp[q];
            xi[4 * q] = v.x; xi[4 * q + 1] = v.y; xi[4 * q + 2] = v.z; xi[4 * q + 3] = v.w;
        }
#pragma unroll
        for (int j = 0; j < F1; j++) {
            float s = 0.0f;
#pragma unroll
            for (int k = 0; k < F0; k++) s += xi[k] * sW1a[k * F1 + j];
            xw1[(size_t)n * F1 + j] = s;
        }
    }
    gbar(bar, NB * 1);

    // ---- P1: agg1[dst*16+f] += xw1[src*16+f] — lanes 0..15 cover one edge's
    //      features so the 16 same-line atomics merge per instruction ----
    for (int idx = gid; idx < N_EDGES * F1; idx += GT) {
        int e = idx >> 4;
        int f = idx & 15;
        int src = ei[e];
        int dst = ei[N_EDGES + e];
        atomicAdd(&agg1[(size_t)dst * F1 + f], xw1[(size_t)src * F1 + f]);
    }
    gbar(bar, NB * 2);

    // ---- P2: u=relu(xw1+agg1+b1a); h=relu(u@W1b+b1b); h1w = h@W2a ----
    for (int n = gid; n < N_NODES; n += GT) {
        float u[F1];
#pragma unroll
        for (int k = 0; k < F1; k++)
            u[k] = fmaxf(xw1[(size_t)n * F1 + k] + agg1[(size_t)n * F1 + k] + sb1a[k], 0.0f);
        float h[F1];
#pragma unroll
        for (int j = 0; j < F1; j++) {
            float s = sb1b[j];
#pragma unroll
            for (int k = 0; k < F1; k++) s += u[k] * sW1b[k * F1 + j];
            h[j] = fmaxf(s, 0.0f);
        }
#pragma unroll
        for (int j = 0; j < F2; j++) {
            float s = 0.0f;
#pragma unroll
            for (int k = 0; k < F1; k++) s += h[k] * sW2a[k * F2 + j];
            h1w[(size_t)n * F2 + j] = s;
        }
    }
    gbar(bar, NB * 3);

    // ---- P3: agg2[dst*8+f] += h1w[src*8+f] — lanes 0..7 per edge ----
    for (int idx = gid; idx < N_EDGES * F2; idx += GT) {
        int e = idx >> 3;
        int f = idx & 7;
        int src = ei[e];
        int dst = ei[N_EDGES + e];
        atomicAdd(&agg2[(size_t)dst * F2 + f], h1w[(size_t)src * F2 + f]);
    }
    gbar(bar, NB * 4);

    // ---- P4: layer-2 tail + mean-pool partials (LDS) + flush ----
    for (int n = gid; n < N_NODES; n += GT) {
        float u[F2];
#pragma unroll
        for (int k = 0; k < F2; k++)
            u[k] = fmaxf(h1w[(size_t)n * F2 + k] + agg2[(size_t)n * F2 + k] + sb2a[k], 0.0f);
        float v[F2];
#pragma unroll
        for (int j = 0; j < F2; j++) {
            float s = sb2b[j];
#pragma unroll
            for (int k = 0; k < F2; k++) s += u[k] * sW2b[k * F2 + j];
            v[j] = fmaxf(s, 0.0f);
        }
        int g = batch[n];
#pragma unroll
        for (int j = 0; j < F2; j++) atomicAdd(&ls[g * F2 + j], v[j]);
        atomicAdd(&lc[g], 1.0f);
    }
    __syncthreads();
    for (int i = t; i < NGRAPH * F2; i += NT)
        if (ls[i] != 0.0f) atomicAdd(&gsum[i], ls[i]);
    if (t < NGRAPH && lc[t] != 0.0f) atomicAdd(&gcnt[t], lc[t]);
    gbar(bar, NB * 5);

    // ---- P5: FC + log_softmax (block 0 only) ----
    if (blockIdx.x == 0 && t < NGRAPH) {
        int g = t;
        float cnt = fmaxf(gcnt[g], 1.0f);
        float p[F2];
#pragma unroll
        for (int f = 0; f < F2; f++) p[f] = gsum[g * F2 + f] / cnt;
        float l[NCLS];
#pragma unroll
        for (int c = 0; c < NCLS; c++) {
            float s = bfc[c];
#pragma unroll
            for (int f = 0; f < F2; f++) s += p[f] * Wfc[f * NCLS + c];
            l[c] = s;
        }
        float m = -INFINITY;
#pragma unroll
        for (int c = 0; c < NCLS; c++) m = fmaxf(m, l[c]);
        float s = 0.0f;
#pragma unroll
        for (int c = 0; c < NCLS; c++) s += expf(l[c] - m);
        float lse = m + logf(s);
#pragma unroll
        for (int c = 0; c < NCLS; c++) out[g * NCLS + c] = l[c] - lse;
    }
}

extern "C" void kernel_launch(void* const* d_in, const int* in_sizes, int n_in,
                              void* d_out, int out_size, void* d_ws, size_t ws_size,
                              hipStream_t stream) {
    const float* x    = (const float*)d_in[0];
    const int*   ei   = (const int*)d_in[1];
    const int*   batch= (const int*)d_in[2];
    const float* W1a  = (const float*)d_in[3];
    const float* b1a  = (const float*)d_in[4];
    const float* W1b  = (const float*)d_in[5];
    const float* b1b  = (const float*)d_in[6];
    const float* W2a  = (const float*)d_in[7];
    const float* b2a  = (const float*)d_in[8];
    const float* W2b  = (const float*)d_in[9];
    const float* b2b  = (const float*)d_in[10];
    const float* Wfc  = (const float*)d_in[11];
    const float* bfc  = (const float*)d_in[12];
    float* out = (float*)d_out;

    // workspace layout: [agg1 | agg2] (kernel-zeroed) [gsum|gcnt|bar] (memset) [xw1|h1w]
    float* ws   = (float*)d_ws;
    float* agg1 = ws;                                   // 100000*16
    float* agg2 = agg1 + (size_t)N_NODES * F1;          // 100000*8
    float* gsum = agg2 + (size_t)N_NODES * F2;          // 64*8
    float* gcnt = gsum + NGRAPH * F2;                   // 64
    int*   bar  = (int*)(gcnt + NGRAPH);                // 16 ints
    float* xw1  = (float*)(bar + 16);                   // 100000*16
    float* h1w  = xw1 + (size_t)N_NODES * F1;           // 100000*8

    // tiny memset: gsum + gcnt + bar only (2.4 KB); aggs zeroed in-kernel
    hipMemsetAsync(gsum, 0, (NGRAPH * F2 + NGRAPH) * sizeof(float) + 16 * sizeof(int), stream);

    fused_k<<<NB, NT, 0, stream>>>(x, ei, batch,
                                   W1a, b1a, W1b, b1b, W2a, b2a, W2b, b2b, Wfc, bfc,
                                   xw1, agg1, h1w, agg2, gsum, gcnt, bar, out);
}